// Round 9
// baseline (484.886 us; speedup 1.0000x reference)
//
#include <hip/hip_runtime.h>
#include <stdint.h>

// KNN BC policy: B=1024 x D=512 queries vs N=100000 bank, top-16 L2, mean of acts [1024,32].
// R9 = R7's high-occupancy geometry (4 waves x 64n x 64q, BK=32) + triple-buffered LDS
// (1 barrier per K-step instead of 2) + two 128-row slabs per block (selection registers
// persist -> top-8 per 256 rows -> 3136 cands/query, R8's cheap topk).

#define NQ     1024
#define DIM    512
#define NB     100000
#define NPAD   100352          // 392 * 256
#define NBLK   392             // n-blocks of 256 rows
#define ADIM   32
#define KNB    16
#define NCAND  (NBLK * 8)      // 3136 candidates per query
#define QUARTER (NCAND / 4)    // 784 per wave in topk

typedef __attribute__((ext_vector_type(8)))  _Float16 half8;
typedef __attribute__((ext_vector_type(16))) float f32x16;

__device__ inline int   f2i(float f) { union { float f; int i; } u; u.f = f; return u.i; }
__device__ inline float i2f(int i)   { union { int i; float f; } u; u.i = i; return u.f; }

__device__ inline void gload16(const void* g, void* l) {
  __builtin_amdgcn_global_load_lds(
      (const __attribute__((address_space(1))) unsigned int*)g,
      (__attribute__((address_space(3))) unsigned int*)l, 16, 0, 0);
}

// ---------------- conversion + norms ----------------
__global__ __launch_bounds__(256) void convert_bank_kernel(
    const float* __restrict__ bank, _Float16* __restrict__ bank16,
    float* __restrict__ b2) {
  const int row  = blockIdx.x * 4 + (threadIdx.x >> 6);
  const int lane = threadIdx.x & 63;
  if (row < NB) {
    const float* src = bank + (size_t)row * DIM + lane * 8;
    const float4 a = ((const float4*)src)[0];
    const float4 b = ((const float4*)src)[1];
    float ss = a.x*a.x + a.y*a.y + a.z*a.z + a.w*a.w
             + b.x*b.x + b.y*b.y + b.z*b.z + b.w*b.w;
    #pragma unroll
    for (int o = 32; o; o >>= 1) ss += __shfl_xor(ss, o);
    half8 o8;
    o8[0]=(_Float16)a.x; o8[1]=(_Float16)a.y; o8[2]=(_Float16)a.z; o8[3]=(_Float16)a.w;
    o8[4]=(_Float16)b.x; o8[5]=(_Float16)b.y; o8[6]=(_Float16)b.z; o8[7]=(_Float16)b.w;
    *(half8*)(bank16 + (size_t)row * DIM + lane * 8) = o8;
    if (lane == 0) b2[row] = ss;
  } else {
    half8 z = {0,0,0,0,0,0,0,0};
    *(half8*)(bank16 + (size_t)row * DIM + lane * 8) = z;
    if (lane == 0) b2[row] = 1e30f;   // pad rows never selected
  }
}

__global__ __launch_bounds__(256) void convert_obs_kernel(
    const float* __restrict__ obs, _Float16* __restrict__ o16) {
  const int row  = blockIdx.x * 4 + (threadIdx.x >> 6);
  const int lane = threadIdx.x & 63;
  const float* src = obs + (size_t)row * DIM + lane * 8;
  const float4 a = ((const float4*)src)[0];
  const float4 b = ((const float4*)src)[1];
  half8 o8;
  o8[0]=(_Float16)a.x; o8[1]=(_Float16)a.y; o8[2]=(_Float16)a.z; o8[3]=(_Float16)a.w;
  o8[4]=(_Float16)b.x; o8[5]=(_Float16)b.y; o8[6]=(_Float16)b.z; o8[7]=(_Float16)b.w;
  *(half8*)(o16 + (size_t)row * DIM + lane * 8) = o8;
}

// ---------------- triple-buffered async GEMM + in-register top-8 ----------------
// Block 256 thr = 4 waves (2wn x 2wq); wave = 64n x 64q (acc[2][2], 64 AGPR).
// 32 K-steps = 2 slabs of 128n x (K=512). Per kt per wave: 4 gload_lds, 8 ds_read_b128,
// 8 MFMA, ONE s_barrier. vmcnt(4) counted waits keep next tile's loads in flight.
__global__ __launch_bounds__(256) void gemm_select_kernel(
    const _Float16* __restrict__ A16,   // bank fp16 [NPAD][512]
    const _Float16* __restrict__ B16,   // obs  fp16 [1024][512]
    const float* __restrict__ b2,
    float2* __restrict__ cand) {
  __shared__ _Float16 As[3][128 * 32];   // 3 x 8 KB
  __shared__ _Float16 Bs[3][128 * 32];   // 3 x 8 KB
  __shared__ float    b2s[256];

  const int tid = threadIdx.x;
  const int l   = tid & 63;
  const int w   = tid >> 6;
  const int wn  = w >> 1;
  const int wq  = w & 1;
  const int rl  = l & 31;
  const int kl  = l >> 5;

  // bijective XCD-chunk swizzle: 3136 = 8 x 392; qblk fast within chunk
  const int bid  = blockIdx.x;
  const int sb   = (bid & 7) * (NBLK * 8 / 8) + (bid >> 3);
  const int nblk = sb >> 3;
  const int qblk = sb & 7;
  const int n0   = nblk * 256;
  const int q0   = qblk * 128;

  b2s[tid] = b2[n0 + tid];   // 256 entries, 256 threads

  f32x16 acc[2][2];
  #pragma unroll
  for (int i = 0; i < 2; ++i)
    #pragma unroll
    for (int j = 0; j < 2; ++j)
      #pragma unroll
      for (int r = 0; r < 16; ++r) acc[i][j][r] = 0.f;

  // staging: wave w stages A-slabs rows {2w*16.., (2w+1)*16..} and same B rows.
  // dest linear (HW: base + lane*16); source chunk inverse-swizzled c ^ ((row>>1)&3),
  // row-in-slab = l>>2 -> swizzle term (l>>3)&3.
  const int sr = l >> 2;
  const int sc = (l & 3) ^ ((l >> 3) & 3);
  const _Float16* gA0 = A16 + (size_t)(n0 + (2 * w) * 16 + sr) * DIM + sc * 8;
  const _Float16* gA1 = gA0 + (size_t)16 * DIM;
  const _Float16* gB0 = B16 + (size_t)(q0 + (2 * w) * 16 + sr) * DIM + sc * 8;
  const _Float16* gB1 = gB0 + (size_t)16 * DIM;

  auto STAGE = [&](int t) {
    const int buf = t % 3;
    const size_t ka = (size_t)(t >> 4) * 128 * DIM + (size_t)(t & 15) * 32;
    const size_t kb = (size_t)(t & 15) * 32;
    char* ab = (char*)(&As[0][0]) + buf * 8192 + (2 * w) * 1024;
    char* bb = (char*)(&Bs[0][0]) + buf * 8192 + (2 * w) * 1024;
    gload16(gA0 + ka, ab);
    gload16(gA1 + ka, ab + 1024);
    gload16(gB0 + kb, bb);
    gload16(gB1 + kb, bb + 1024);
  };

  STAGE(0);
  STAGE(1);

  const int rowa0 = wn * 64 + rl, rowa1 = rowa0 + 32;
  const int rowb0 = wq * 64 + rl, rowb1 = rowb0 + 32;
  const int sw = (rl >> 1) & 3;   // loop-invariant swizzle term (rows base mult. of 32)

  float ts[2][8]; int ti[2][8];
  #pragma unroll
  for (int qs = 0; qs < 2; ++qs)
    #pragma unroll
    for (int i = 0; i < 8; ++i) { ts[qs][i] = 1e38f; ti[qs][i] = -1; }

  auto COMPUTE = [&](int t) {
    const int buf = t % 3;
    const half8* A8 = (const half8*)((char*)(&As[0][0]) + buf * 8192);
    const half8* B8 = (const half8*)((char*)(&Bs[0][0]) + buf * 8192);
    __builtin_amdgcn_sched_barrier(0);
    __builtin_amdgcn_s_setprio(1);
    #pragma unroll
    for (int ks = 0; ks < 2; ++ks) {
      const int c = ks * 2 + kl;
      const half8 a0 = A8[rowa0 * 4 + (c ^ sw)];
      const half8 a1 = A8[rowa1 * 4 + (c ^ sw)];
      const half8 b0 = B8[rowb0 * 4 + (c ^ sw)];
      const half8 b1 = B8[rowb1 * 4 + (c ^ sw)];
      acc[0][0] = __builtin_amdgcn_mfma_f32_32x32x16_f16(a0, b0, acc[0][0], 0, 0, 0);
      acc[0][1] = __builtin_amdgcn_mfma_f32_32x32x16_f16(a0, b1, acc[0][1], 0, 0, 0);
      acc[1][0] = __builtin_amdgcn_mfma_f32_32x32x16_f16(a1, b0, acc[1][0], 0, 0, 0);
      acc[1][1] = __builtin_amdgcn_mfma_f32_32x32x16_f16(a1, b1, acc[1][1], 0, 0, 0);
    }
    __builtin_amdgcn_s_setprio(0);
    __builtin_amdgcn_sched_barrier(0);
  };

  // selection-insert: fold acc scores into per-thread ts/ti for slab `sub`, re-zero acc
  auto INSERT = [&](int sub) {
    #pragma unroll
    for (int qs = 0; qs < 2; ++qs) {
      #pragma unroll
      for (int ns = 0; ns < 2; ++ns) {
        #pragma unroll
        for (int r = 0; r < 16; ++r) {
          const int nl = sub * 128 + wn * 64 + ns * 32 + (r & 3) + 8 * (r >> 2) + 4 * kl;
          const float sc2 = fmaf(0.5f, b2s[nl], -acc[ns][qs][r]);
          if (sc2 < ts[qs][7]) {
            float cs = sc2; int ci = n0 + nl;
            #pragma unroll
            for (int p = 0; p < 8; ++p) {
              if (cs < ts[qs][p]) {
                float tf = ts[qs][p]; ts[qs][p] = cs; cs = tf;
                int   tt = ti[qs][p]; ti[qs][p] = ci; ci = tt;
              }
            }
          }
          acc[ns][qs][r] = 0.f;
        }
      }
    }
  };

  // ---- slab 0: t = 0..15 ----
  #pragma unroll 1
  for (int t = 0; t < 16; ++t) {
    asm volatile("s_waitcnt vmcnt(4)" ::: "memory");   // t's 4 loads done; t+1's in flight
    __builtin_amdgcn_s_barrier();                       // also proves buf(t+2) reads finished
    STAGE(t + 2);
    COMPUTE(t);
  }
  INSERT(0);
  // ---- slab 1: t = 16..29 with prefetch, then peeled 30, 31 ----
  #pragma unroll 1
  for (int t = 16; t < 30; ++t) {
    asm volatile("s_waitcnt vmcnt(4)" ::: "memory");
    __builtin_amdgcn_s_barrier();
    STAGE(t + 2);
    COMPUTE(t);
  }
  asm volatile("s_waitcnt vmcnt(4)" ::: "memory");
  __builtin_amdgcn_s_barrier();
  COMPUTE(30);
  asm volatile("s_waitcnt vmcnt(0)" ::: "memory");
  __builtin_amdgcn_s_barrier();
  COMPUTE(31);
  INSERT(1);

  __syncthreads();   // all LDS reads done before mbuf overlay

  // ---- lane-pair (l^32) head-merge -> per-(wn,wq,qs,q) top-8 lists in mbuf ----
  float2* mbuf = (float2*)(&As[0][0]);   // 16 KB overlay
  #pragma unroll
  for (int qs = 0; qs < 2; ++qs) {
    float2* mrow = mbuf + ((((wn * 2 + wq) * 2 + qs) * 32) + rl) * 8;
    for (int k = 0; k < 8; ++k) {
      const float ov = __shfl_xor(ts[qs][0], 32);
      const int   oi = __shfl_xor(ti[qs][0], 32);
      const bool mine = (ts[qs][0] < ov) || (ts[qs][0] == ov && kl == 0);
      const float wv = mine ? ts[qs][0] : ov;
      const int   wi = mine ? ti[qs][0] : oi;
      if (mine) {
        #pragma unroll
        for (int p = 0; p < 7; ++p) { ts[qs][p] = ts[qs][p+1]; ti[qs][p] = ti[qs][p+1]; }
        ts[qs][7] = 1e38f; ti[qs][7] = -1;
      }
      if (kl == 0) mrow[k] = make_float2(wv, i2f(wi));
    }
  }
  __syncthreads();

  // ---- cross-wn merge (sorted 8+8 -> 8) + global store; 128 q-slots ----
  if (tid < 128) {
    const int wq_f = tid >> 6;
    const int qs_f = (tid >> 5) & 1;
    const int rl_f = tid & 31;
    const float2* pa = mbuf + ((((0 * 2 + wq_f) * 2 + qs_f) * 32) + rl_f) * 8;
    const float2* pb = mbuf + ((((1 * 2 + wq_f) * 2 + qs_f) * 32) + rl_f) * 8;
    float av[8], bv[8]; int ai[8], bi[8];
    #pragma unroll
    for (int j = 0; j < 8; ++j) {
      const float2 ta = pa[j]; av[j] = ta.x; ai[j] = f2i(ta.y);
      const float2 tb = pb[j]; bv[j] = tb.x; bi[j] = f2i(tb.y);
    }
    const int q = q0 + wq_f * 64 + qs_f * 32 + rl_f;
    float2* outp = cand + ((size_t)q * NBLK + nblk) * 8;
    for (int k = 0; k < 8; ++k) {
      const bool ta = (av[0] <= bv[0]);
      outp[k] = make_float2(ta ? av[0] : bv[0], i2f(ta ? ai[0] : bi[0]));
      if (ta) {
        #pragma unroll
        for (int p = 0; p < 7; ++p) { av[p] = av[p+1]; ai[p] = ai[p+1]; }
        av[7] = 1e38f;
      } else {
        #pragma unroll
        for (int p = 0; p < 7; ++p) { bv[p] = bv[p+1]; bi[p] = bi[p+1]; }
        bv[7] = 1e38f;
      }
    }
  }
}

// ---------------- per-query candidate merge + exact rerank ----------------
__global__ __launch_bounds__(256) void topk_kernel(
    const float2* __restrict__ cand, const float* __restrict__ obs,
    const float* __restrict__ bank, const float* __restrict__ acts,
    float* __restrict__ out) {
  __shared__ float2 lc[NCAND];       // 25088 B
  __shared__ float2 wtop[128];
  __shared__ int   selidx[32];
  __shared__ float exd[32];
  __shared__ int   sel2[16];
  const int q    = blockIdx.x;
  const int tid  = threadIdx.x;
  const int lane = tid & 63;
  const int w    = tid >> 6;

  for (int i = tid; i < NCAND; i += 256) lc[i] = cand[(size_t)q * NCAND + i];
  __syncthreads();

  float ts[10]; int ti[10];
  #pragma unroll
  for (int i = 0; i < 10; ++i) { ts[i] = 1e38f; ti[i] = -1; }
  for (int i = w * QUARTER + lane; i < (w + 1) * QUARTER; i += 64) {
    const float2 e = lc[i];
    const float s = e.x;
    if (s < ts[9]) {
      float cs = s; int ci = f2i(e.y);
      #pragma unroll
      for (int pp = 0; pp < 10; ++pp) {
        if (cs < ts[pp]) {
          float tf = ts[pp]; ts[pp] = cs; cs = tf;
          int   tt = ti[pp]; ti[pp] = ci; ci = tt;
        }
      }
    }
  }
  for (int k = 0; k < 32; ++k) {
    float bv = ts[0]; int bi = ti[0]; int bl = lane;
    #pragma unroll
    for (int o = 32; o; o >>= 1) {
      float ov = __shfl_xor(bv, o); int oi = __shfl_xor(bi, o); int ol = __shfl_xor(bl, o);
      if (ov < bv || (ov == bv && ol < bl)) { bv = ov; bi = oi; bl = ol; }
    }
    if (lane == bl) {
      #pragma unroll
      for (int pp = 0; pp < 9; ++pp) { ts[pp] = ts[pp+1]; ti[pp] = ti[pp+1]; }
      ts[9] = 1e38f; ti[9] = -1;
    }
    if (lane == 0) wtop[w * 32 + k] = make_float2(bv, i2f(bi));
  }
  __syncthreads();

  if (w == 0) {
    float2 e0 = wtop[lane], e1 = wtop[64 + lane];
    float s0 = e0.x, s1 = e1.x;
    int   i0 = f2i(e0.y), i1 = f2i(e1.y);
    if (s1 < s0) { float tf = s0; s0 = s1; s1 = tf; int tt = i0; i0 = i1; i1 = tt; }
    for (int k = 0; k < 32; ++k) {
      float bv = s0; int bi = i0; int bl = lane;
      #pragma unroll
      for (int o = 32; o; o >>= 1) {
        float ov = __shfl_xor(bv, o); int oi = __shfl_xor(bi, o); int ol = __shfl_xor(bl, o);
        if (ov < bv || (ov == bv && ol < bl)) { bv = ov; bi = oi; bl = ol; }
      }
      if (lane == bl) { s0 = s1; i0 = i1; s1 = 1e38f; i1 = -1; }
      if (lane == 0) selidx[k] = bi;
    }
  }
  __syncthreads();

  const float* qp = obs + (size_t)q * DIM + lane * 8;
  const float4 qa = ((const float4*)qp)[0];
  const float4 qb = ((const float4*)qp)[1];
  for (int c2 = w; c2 < 32; c2 += 4) {
    const int idx = selidx[c2];
    const float* bp_ = bank + (size_t)idx * DIM + lane * 8;
    const float4 ba = ((const float4*)bp_)[0];
    const float4 bb = ((const float4*)bp_)[1];
    const float d0 = qa.x-ba.x, d1 = qa.y-ba.y, d2 = qa.z-ba.z, d3 = qa.w-ba.w;
    const float d4 = qb.x-bb.x, d5 = qb.y-bb.y, d6 = qb.z-bb.z, d7 = qb.w-bb.w;
    float ss = d0*d0 + d1*d1 + d2*d2 + d3*d3 + d4*d4 + d5*d5 + d6*d6 + d7*d7;
    #pragma unroll
    for (int o = 32; o; o >>= 1) ss += __shfl_xor(ss, o);
    if (lane == 0) exd[c2] = ss;
  }
  __syncthreads();

  if (w == 0) {
    const float v  = (lane < 32) ? exd[lane] : 1e38f;
    const int   id = (lane < 32) ? selidx[lane] : -1;
    float lastv = -1e38f; int lastp = -1;
    for (int k = 0; k < 16; ++k) {
      float bv = 1e38f; int bi = -1; int bp = 64;
      const bool gt = (v > lastv) || (v == lastv && lane > lastp);
      if (gt) { bv = v; bi = id; bp = lane; }
      #pragma unroll
      for (int o = 32; o; o >>= 1) {
        float ov = __shfl_xor(bv, o); int oi = __shfl_xor(bi, o); int op = __shfl_xor(bp, o);
        if (ov < bv || (ov == bv && op < bp)) { bv = ov; bi = oi; bp = op; }
      }
      if (lane == 0) sel2[k] = bi;
      lastv = bv; lastp = bp;
    }
  }
  __syncthreads();

  if (tid < ADIM) {
    float s = 0.f;
    #pragma unroll
    for (int t2 = 0; t2 < KNB; ++t2) s += acts[(size_t)sel2[t2] * ADIM + tid];
    out[(size_t)q * ADIM + tid] = s * (1.0f / KNB);
  }
}

// ---------------- host launch ----------------
extern "C" void kernel_launch(void* const* d_in, const int* in_sizes, int n_in,
                              void* d_out, int out_size, void* d_ws, size_t ws_size,
                              hipStream_t stream) {
  const float* obs  = (const float*)d_in[0];
  const float* bank = (const float*)d_in[1];
  const float* acts = (const float*)d_in[2];
  float* out = (float*)d_out;
  char* ws = (char*)d_ws;

  size_t off = 0;
  auto take = [&](size_t b) { size_t o = off; off += (b + 255) & ~(size_t)255; return o; };
  const size_t off_b16  = take((size_t)NPAD * DIM * 2);          // 102.8 MB
  const size_t off_o16  = take((size_t)NQ * DIM * 2);            // 1 MB
  const size_t off_b2   = take((size_t)NPAD * 4);                // 0.4 MB
  const size_t off_cand = take((size_t)NQ * NCAND * 8);          // 25.7 MB

  _Float16* bank16 = (_Float16*)(ws + off_b16);
  _Float16* obs16  = (_Float16*)(ws + off_o16);
  float*  b2   = (float*)(ws + off_b2);
  float2* cand = (float2*)(ws + off_cand);

  convert_bank_kernel<<<NPAD / 4, 256, 0, stream>>>(bank, bank16, b2);
  convert_obs_kernel<<<NQ / 4, 256, 0, stream>>>(obs, obs16);
  gemm_select_kernel<<<NBLK * 8, 256, 0, stream>>>(bank16, obs16, b2, cand);
  topk_kernel<<<NQ, 256, 0, stream>>>(cand, obs, bank, acts, out);
}

// Round 10
// 388.267 us; speedup vs baseline: 1.2488x; 1.2488x over previous
//
#include <hip/hip_runtime.h>
#include <stdint.h>

// KNN BC policy: B=1024 x D=512 queries vs N=100000 bank, top-16 L2, mean of acts [1024,32].
// R10: gemm reverted byte-for-byte to R7 (best measured: 256us, 52 VGPR, 40% occ;
// counted-vmcnt async, dbuf, 4 waves of 64n x 64q). topk rebuilt for parallelism:
// 512 thr, direct-global coalesced scan (no LDS staging), 8-wave extraction,
// rerank spread over 8 waves. R8/R9 lesson: occupancy >> per-wave work here.

#define NQ     1024
#define DIM    512
#define NB     100000
#define NPAD   100352          // 784 * 128
#define NBLK   784             // n-blocks of 128 rows
#define ADIM   32
#define KNB    16
#define NCAND  (NBLK * 8)      // 6272 candidates per query
#define WSPAN  (NCAND / 8)     // 784 per wave in topk

typedef __attribute__((ext_vector_type(8)))  _Float16 half8;
typedef __attribute__((ext_vector_type(16))) float f32x16;

__device__ inline int   f2i(float f) { union { float f; int i; } u; u.f = f; return u.i; }
__device__ inline float i2f(int i)   { union { int i; float f; } u; u.i = i; return u.f; }

__device__ inline void gload16(const void* g, void* l) {
  __builtin_amdgcn_global_load_lds(
      (const __attribute__((address_space(1))) unsigned int*)g,
      (__attribute__((address_space(3))) unsigned int*)l, 16, 0, 0);
}

// ---------------- conversion + norms ----------------
__global__ __launch_bounds__(256) void convert_bank_kernel(
    const float* __restrict__ bank, _Float16* __restrict__ bank16,
    float* __restrict__ b2) {
  const int row  = blockIdx.x * 4 + (threadIdx.x >> 6);
  const int lane = threadIdx.x & 63;
  if (row < NB) {
    const float* src = bank + (size_t)row * DIM + lane * 8;
    const float4 a = ((const float4*)src)[0];
    const float4 b = ((const float4*)src)[1];
    float ss = a.x*a.x + a.y*a.y + a.z*a.z + a.w*a.w
             + b.x*b.x + b.y*b.y + b.z*b.z + b.w*b.w;
    #pragma unroll
    for (int o = 32; o; o >>= 1) ss += __shfl_xor(ss, o);
    half8 o8;
    o8[0]=(_Float16)a.x; o8[1]=(_Float16)a.y; o8[2]=(_Float16)a.z; o8[3]=(_Float16)a.w;
    o8[4]=(_Float16)b.x; o8[5]=(_Float16)b.y; o8[6]=(_Float16)b.z; o8[7]=(_Float16)b.w;
    *(half8*)(bank16 + (size_t)row * DIM + lane * 8) = o8;
    if (lane == 0) b2[row] = ss;
  } else {
    half8 z = {0,0,0,0,0,0,0,0};
    *(half8*)(bank16 + (size_t)row * DIM + lane * 8) = z;
    if (lane == 0) b2[row] = 1e30f;   // pad rows never selected
  }
}

__global__ __launch_bounds__(256) void convert_obs_kernel(
    const float* __restrict__ obs, _Float16* __restrict__ o16) {
  const int row  = blockIdx.x * 4 + (threadIdx.x >> 6);
  const int lane = threadIdx.x & 63;
  const float* src = obs + (size_t)row * DIM + lane * 8;
  const float4 a = ((const float4*)src)[0];
  const float4 b = ((const float4*)src)[1];
  half8 o8;
  o8[0]=(_Float16)a.x; o8[1]=(_Float16)a.y; o8[2]=(_Float16)a.z; o8[3]=(_Float16)a.w;
  o8[4]=(_Float16)b.x; o8[5]=(_Float16)b.y; o8[6]=(_Float16)b.z; o8[7]=(_Float16)b.w;
  *(half8*)(o16 + (size_t)row * DIM + lane * 8) = o8;
}

// ---------------- async-pipelined GEMM + in-register top-8 (R7 verbatim) ----------------
__global__ __launch_bounds__(256, 4) void gemm_select_kernel(
    const _Float16* __restrict__ A16,   // bank fp16 [NPAD][512]
    const _Float16* __restrict__ B16,   // obs  fp16 [1024][512]
    const float* __restrict__ b2,
    float2* __restrict__ cand) {
  __shared__ _Float16 As[2][128 * 32];   // 2 x 8 KB
  __shared__ _Float16 Bs[2][128 * 32];   // 2 x 8 KB
  __shared__ float    b2s[128];

  const int tid = threadIdx.x;
  const int l   = tid & 63;
  const int w   = tid >> 6;
  const int wn  = w >> 1;
  const int wq  = w & 1;
  const int rl  = l & 31;
  const int kl  = l >> 5;

  // bijective XCD-chunk swizzle: 6272 = 8 x 784; q fast within chunk
  const int bid  = blockIdx.x;
  const int sb   = (bid & 7) * (NBLK * 8 / 8) + (bid >> 3);
  const int nblk = sb >> 3;
  const int qblk = sb & 7;
  const int n0   = nblk * 128;
  const int q0   = qblk * 128;

  if (tid < 128) b2s[tid] = b2[n0 + tid];

  f32x16 acc[2][2];
  #pragma unroll
  for (int i = 0; i < 2; ++i)
    #pragma unroll
    for (int j = 0; j < 2; ++j)
      #pragma unroll
      for (int r = 0; r < 16; ++r) acc[i][j][r] = 0.f;

  const int sr = l >> 2;
  const int sc = (l & 3) ^ ((l >> 3) & 3);
  const _Float16* gA0 = A16 + (size_t)(n0 + (2 * w) * 16 + sr) * DIM + sc * 8;
  const _Float16* gA1 = gA0 + (size_t)16 * DIM;
  const _Float16* gB0 = B16 + (size_t)(q0 + (2 * w) * 16 + sr) * DIM + sc * 8;
  const _Float16* gB1 = gB0 + (size_t)16 * DIM;

  auto STAGE = [&](int t) {
    const int buf = t & 1;
    const int k0  = t * 32;
    char* ab = (char*)(&As[buf][0]) + (2 * w) * 1024;
    char* bb = (char*)(&Bs[buf][0]) + (2 * w) * 1024;
    gload16(gA0 + k0, ab);
    gload16(gA1 + k0, ab + 1024);
    gload16(gB0 + k0, bb);
    gload16(gB1 + k0, bb + 1024);
  };

  STAGE(0);
  STAGE(1);

  const int rowa0 = wn * 64 + rl, rowa1 = rowa0 + 32;
  const int rowb0 = wq * 64 + rl, rowb1 = rowb0 + 32;
  const int swa0 = (rowa0 >> 1) & 3, swa1 = (rowa1 >> 1) & 3;
  const int swb0 = (rowb0 >> 1) & 3, swb1 = (rowb1 >> 1) & 3;

  #pragma unroll 1
  for (int t = 0; t < 15; ++t) {
    asm volatile("s_waitcnt vmcnt(4)" ::: "memory");   // t's loads done; t+1's in flight
    __builtin_amdgcn_s_barrier();
    __builtin_amdgcn_sched_barrier(0);
    const half8* A8 = (const half8*)(&As[t & 1][0]);
    const half8* B8 = (const half8*)(&Bs[t & 1][0]);
    #pragma unroll
    for (int ks = 0; ks < 2; ++ks) {
      const int c = ks * 2 + kl;
      const half8 a0 = A8[rowa0 * 4 + (c ^ swa0)];
      const half8 a1 = A8[rowa1 * 4 + (c ^ swa1)];
      const half8 b0 = B8[rowb0 * 4 + (c ^ swb0)];
      const half8 b1 = B8[rowb1 * 4 + (c ^ swb1)];
      acc[0][0] = __builtin_amdgcn_mfma_f32_32x32x16_f16(a0, b0, acc[0][0], 0, 0, 0);
      acc[0][1] = __builtin_amdgcn_mfma_f32_32x32x16_f16(a0, b1, acc[0][1], 0, 0, 0);
      acc[1][0] = __builtin_amdgcn_mfma_f32_32x32x16_f16(a1, b0, acc[1][0], 0, 0, 0);
      acc[1][1] = __builtin_amdgcn_mfma_f32_32x32x16_f16(a1, b1, acc[1][1], 0, 0, 0);
    }
    __builtin_amdgcn_sched_barrier(0);
    __builtin_amdgcn_s_barrier();   // all reads of buf done -> safe to overwrite
    if (t < 14) STAGE(t + 2);
  }
  {
    asm volatile("s_waitcnt vmcnt(0)" ::: "memory");
    __builtin_amdgcn_s_barrier();
    __builtin_amdgcn_sched_barrier(0);
    const half8* A8 = (const half8*)(&As[1][0]);
    const half8* B8 = (const half8*)(&Bs[1][0]);
    #pragma unroll
    for (int ks = 0; ks < 2; ++ks) {
      const int c = ks * 2 + kl;
      const half8 a0 = A8[rowa0 * 4 + (c ^ swa0)];
      const half8 a1 = A8[rowa1 * 4 + (c ^ swa1)];
      const half8 b0 = B8[rowb0 * 4 + (c ^ swb0)];
      const half8 b1 = B8[rowb1 * 4 + (c ^ swb1)];
      acc[0][0] = __builtin_amdgcn_mfma_f32_32x32x16_f16(a0, b0, acc[0][0], 0, 0, 0);
      acc[0][1] = __builtin_amdgcn_mfma_f32_32x32x16_f16(a0, b1, acc[0][1], 0, 0, 0);
      acc[1][0] = __builtin_amdgcn_mfma_f32_32x32x16_f16(a1, b0, acc[1][0], 0, 0, 0);
      acc[1][1] = __builtin_amdgcn_mfma_f32_32x32x16_f16(a1, b1, acc[1][1], 0, 0, 0);
    }
    __builtin_amdgcn_sched_barrier(0);
    __builtin_amdgcn_s_barrier();
  }

  // ---- selection: per qs (two 32q groups), per-lane top-8 over 32 n-scores ----
  float2* mbuf = (float2*)(&As[0][0]);   // 16 KB overlay: [wn][wq][qs][32][8]
  #pragma unroll
  for (int qs = 0; qs < 2; ++qs) {
    float ts[8]; int ti[8];
    #pragma unroll
    for (int i = 0; i < 8; ++i) { ts[i] = 1e38f; ti[i] = -1; }
    #pragma unroll
    for (int ns = 0; ns < 2; ++ns) {
      #pragma unroll
      for (int r = 0; r < 16; ++r) {
        const int nl = wn * 64 + ns * 32 + (r & 3) + 8 * (r >> 2) + 4 * kl;
        const float sc2 = fmaf(0.5f, b2s[nl], -acc[ns][qs][r]);
        if (sc2 < ts[7]) {
          float cs = sc2; int ci = n0 + nl;
          #pragma unroll
          for (int p = 0; p < 8; ++p) {
            if (cs < ts[p]) {
              float tf = ts[p]; ts[p] = cs; cs = tf;
              int   tt = ti[p]; ti[p] = ci; ci = tt;
            }
          }
        }
      }
    }
    float2* mrow = mbuf + ((((wn * 2 + wq) * 2 + qs) * 32) + rl) * 8;
    for (int k = 0; k < 8; ++k) {
      const float ov = __shfl_xor(ts[0], 32);
      const int   oi = __shfl_xor(ti[0], 32);
      const bool mine = (ts[0] < ov) || (ts[0] == ov && kl == 0);
      const float wv = mine ? ts[0] : ov;
      const int   wi = mine ? ti[0] : oi;
      if (mine) {
        #pragma unroll
        for (int p = 0; p < 7; ++p) { ts[p] = ts[p+1]; ti[p] = ti[p+1]; }
        ts[7] = 1e38f; ti[7] = -1;
      }
      if (kl == 0) mrow[k] = make_float2(wv, i2f(wi));
    }
  }
  __syncthreads();

  // ---- cross-wn merge (sorted 8+8 -> 8) + global store; 128 q-slots ----
  if (tid < 128) {
    const int wq_f = tid >> 6;
    const int qs_f = (tid >> 5) & 1;
    const int rl_f = tid & 31;
    const float2* pa = mbuf + ((((0 * 2 + wq_f) * 2 + qs_f) * 32) + rl_f) * 8;
    const float2* pb = mbuf + ((((1 * 2 + wq_f) * 2 + qs_f) * 32) + rl_f) * 8;
    float av[8], bv[8]; int ai[8], bi[8];
    #pragma unroll
    for (int j = 0; j < 8; ++j) {
      const float2 ta = pa[j]; av[j] = ta.x; ai[j] = f2i(ta.y);
      const float2 tb = pb[j]; bv[j] = tb.x; bi[j] = f2i(tb.y);
    }
    const int q = q0 + wq_f * 64 + qs_f * 32 + rl_f;
    float2* outp = cand + ((size_t)q * NBLK + nblk) * 8;
    for (int k = 0; k < 8; ++k) {
      const bool ta = (av[0] <= bv[0]);
      outp[k] = make_float2(ta ? av[0] : bv[0], i2f(ta ? ai[0] : bi[0]));
      if (ta) {
        #pragma unroll
        for (int p = 0; p < 7; ++p) { av[p] = av[p+1]; ai[p] = ai[p+1]; }
        av[7] = 1e38f;
      } else {
        #pragma unroll
        for (int p = 0; p < 7; ++p) { bv[p] = bv[p+1]; bi[p] = bi[p+1]; }
        bv[7] = 1e38f;
      }
    }
  }
}

// ---------------- per-query merge + exact rerank (512 thr, direct-global scan) ----------------
__global__ __launch_bounds__(512) void topk_kernel(
    const float2* __restrict__ cand, const float* __restrict__ obs,
    const float* __restrict__ bank, const float* __restrict__ acts,
    float* __restrict__ out) {
  __shared__ float2 wtop[256];       // 8 waves x 32
  __shared__ int   selidx[32];
  __shared__ float exd[32];
  __shared__ int   sel2[16];
  const int q    = blockIdx.x;
  const int tid  = threadIdx.x;
  const int lane = tid & 63;
  const int w    = tid >> 6;         // 0..7

  // per-lane sorted top-10 over this wave's 784-entry span (coalesced global reads)
  const float2* src = cand + (size_t)q * NCAND + (size_t)w * WSPAN;
  float ts[10]; int ti[10];
  #pragma unroll
  for (int i = 0; i < 10; ++i) { ts[i] = 1e38f; ti[i] = -1; }
  for (int i = lane; i < WSPAN; i += 64) {
    const float2 e = src[i];
    const float s = e.x;
    if (s < ts[9]) {
      float cs = s; int ci = f2i(e.y);
      #pragma unroll
      for (int pp = 0; pp < 10; ++pp) {
        if (cs < ts[pp]) {
          float tf = ts[pp]; ts[pp] = cs; cs = tf;
          int   tt = ti[pp]; ti[pp] = ci; ci = tt;
        }
      }
    }
  }
  // 32 head-extractions per wave -> wtop[w*32 + k]
  for (int k = 0; k < 32; ++k) {
    float bv = ts[0]; int bi = ti[0]; int bl = lane;
    #pragma unroll
    for (int o = 32; o; o >>= 1) {
      float ov = __shfl_xor(bv, o); int oi = __shfl_xor(bi, o); int ol = __shfl_xor(bl, o);
      if (ov < bv || (ov == bv && ol < bl)) { bv = ov; bi = oi; bl = ol; }
    }
    if (lane == bl) {
      #pragma unroll
      for (int pp = 0; pp < 9; ++pp) { ts[pp] = ts[pp+1]; ti[pp] = ti[pp+1]; }
      ts[9] = 1e38f; ti[9] = -1;
    }
    if (lane == 0) wtop[w * 32 + k] = make_float2(bv, i2f(bi));
  }
  __syncthreads();

  // wave 0: 256 wave-winners -> exact top-32. 4 entries/lane, locally sorted, head-merge.
  if (w == 0) {
    float rv[4]; int ri[4];
    #pragma unroll
    for (int j = 0; j < 4; ++j) {
      const float2 e = wtop[j * 64 + lane];
      rv[j] = e.x; ri[j] = f2i(e.y);
    }
    // insertion-sort 4
    #pragma unroll
    for (int a = 1; a < 4; ++a) {
      #pragma unroll
      for (int b2_ = 4 - 1; b2_ >= 1; --b2_) {
        if (rv[b2_] < rv[b2_ - 1]) {
          float tf = rv[b2_]; rv[b2_] = rv[b2_ - 1]; rv[b2_ - 1] = tf;
          int   tt = ri[b2_]; ri[b2_] = ri[b2_ - 1]; ri[b2_ - 1] = tt;
        }
      }
    }
    for (int k = 0; k < 32; ++k) {
      float bv = rv[0]; int bi = ri[0]; int bl = lane;
      #pragma unroll
      for (int o = 32; o; o >>= 1) {
        float ov = __shfl_xor(bv, o); int oi = __shfl_xor(bi, o); int ol = __shfl_xor(bl, o);
        if (ov < bv || (ov == bv && ol < bl)) { bv = ov; bi = oi; bl = ol; }
      }
      if (lane == bl) {
        #pragma unroll
        for (int pp = 0; pp < 3; ++pp) { rv[pp] = rv[pp+1]; ri[pp] = ri[pp+1]; }
        rv[3] = 1e38f; ri[3] = -1;
      }
      if (lane == 0) selidx[k] = bi;
    }
  }
  __syncthreads();

  // exact fp32 distances for the 32 candidates (8 waves, 4 each)
  const float* qp = obs + (size_t)q * DIM + lane * 8;
  const float4 qa = ((const float4*)qp)[0];
  const float4 qb = ((const float4*)qp)[1];
  for (int c2 = w; c2 < 32; c2 += 8) {
    const int idx = selidx[c2];
    const float* bp_ = bank + (size_t)idx * DIM + lane * 8;
    const float4 ba = ((const float4*)bp_)[0];
    const float4 bb = ((const float4*)bp_)[1];
    const float d0 = qa.x-ba.x, d1 = qa.y-ba.y, d2 = qa.z-ba.z, d3 = qa.w-ba.w;
    const float d4 = qb.x-bb.x, d5 = qb.y-bb.y, d6 = qb.z-bb.z, d7 = qb.w-bb.w;
    float ss = d0*d0 + d1*d1 + d2*d2 + d3*d3 + d4*d4 + d5*d5 + d6*d6 + d7*d7;
    #pragma unroll
    for (int o = 32; o; o >>= 1) ss += __shfl_xor(ss, o);
    if (lane == 0) exd[c2] = ss;
  }
  __syncthreads();

  // exact top-16 of 32
  if (w == 0) {
    const float v  = (lane < 32) ? exd[lane] : 1e38f;
    const int   id = (lane < 32) ? selidx[lane] : -1;
    float lastv = -1e38f; int lastp = -1;
    for (int k = 0; k < 16; ++k) {
      float bv = 1e38f; int bi = -1; int bp = 64;
      const bool gt = (v > lastv) || (v == lastv && lane > lastp);
      if (gt) { bv = v; bi = id; bp = lane; }
      #pragma unroll
      for (int o = 32; o; o >>= 1) {
        float ov = __shfl_xor(bv, o); int oi = __shfl_xor(bi, o); int op = __shfl_xor(bp, o);
        if (ov < bv || (ov == bv && op < bp)) { bv = ov; bi = oi; bp = op; }
      }
      if (lane == 0) sel2[k] = bi;
      lastv = bv; lastp = bp;
    }
  }
  __syncthreads();

  if (tid < ADIM) {
    float s = 0.f;
    #pragma unroll
    for (int t2 = 0; t2 < KNB; ++t2) s += acts[(size_t)sel2[t2] * ADIM + tid];
    out[(size_t)q * ADIM + tid] = s * (1.0f / KNB);
  }
}

// ---------------- host launch ----------------
extern "C" void kernel_launch(void* const* d_in, const int* in_sizes, int n_in,
                              void* d_out, int out_size, void* d_ws, size_t ws_size,
                              hipStream_t stream) {
  const float* obs  = (const float*)d_in[0];
  const float* bank = (const float*)d_in[1];
  const float* acts = (const float*)d_in[2];
  float* out = (float*)d_out;
  char* ws = (char*)d_ws;

  size_t off = 0;
  auto take = [&](size_t b) { size_t o = off; off += (b + 255) & ~(size_t)255; return o; };
  const size_t off_b16  = take((size_t)NPAD * DIM * 2);          // 102.8 MB
  const size_t off_o16  = take((size_t)NQ * DIM * 2);            // 1 MB
  const size_t off_b2   = take((size_t)NPAD * 4);                // 0.4 MB
  const size_t off_cand = take((size_t)NQ * NCAND * 8);          // 51.4 MB

  _Float16* bank16 = (_Float16*)(ws + off_b16);
  _Float16* obs16  = (_Float16*)(ws + off_o16);
  float*  b2   = (float*)(ws + off_b2);
  float2* cand = (float2*)(ws + off_cand);

  convert_bank_kernel<<<NPAD / 4, 256, 0, stream>>>(bank, bank16, b2);
  convert_obs_kernel<<<NQ / 4, 256, 0, stream>>>(obs, obs16);
  gemm_select_kernel<<<NBLK * 8, 256, 0, stream>>>(bank16, obs16, b2, cand);
  topk_kernel<<<NQ, 512, 0, stream>>>(cand, obs, bank, acts, out);
}